// Round 4
// baseline (549.395 us; speedup 1.0000x reference)
//
#include <hip/hip_runtime.h>
#include <hip/hip_bf16.h>
#include <stdint.h>

// Problem constants
#define B_    2
#define SQ    2048
#define H_    4096
#define NHEAD 32
#define HDIM  128
#define NGRP  2
#define QKVN  4608          // NH*HD + 2*NG*HD
#define SCALE 0.08838834764831845f   // 1/sqrt(128), coeff=1
#define QSCALE (0.08838834764831845f * 1.4426950408889634f)  // SCALE*log2(e), exp2 softmax

typedef __attribute__((ext_vector_type(8))) short bf16x8;
typedef __attribute__((ext_vector_type(4))) short bf16x4;
typedef __attribute__((ext_vector_type(4))) float f32x4;

__device__ __forceinline__ float b2f(short s) {
  union { float f; unsigned u; } x; x.u = ((unsigned)(unsigned short)s) << 16; return x.f;
}
__device__ __forceinline__ short f2b(float f) {
  union { float f; unsigned u; } x; x.f = f;
  unsigned r = x.u + 0x7fffu + ((x.u >> 16) & 1u);  // RNE
  return (short)(r >> 16);
}
__device__ __forceinline__ void gll16(const void* g, void* l) {
  __builtin_amdgcn_global_load_lds(
      (const __attribute__((address_space(1))) unsigned int*)g,
      (__attribute__((address_space(3))) unsigned int*)l, 16, 0, 0);
}

// ---------------- f32 -> bf16 convert (vectorized) ----------------
__global__ void conv_f32_bf16(const float* __restrict__ x, short* __restrict__ y, int n) {
  int i = (blockIdx.x * blockDim.x + threadIdx.x) * 4;
  if (i >= n) return;
  float4 v = *(const float4*)(x + i);
  union { short s[4]; uint2 u; } o;
  o.s[0] = f2b(v.x); o.s[1] = f2b(v.y); o.s[2] = f2b(v.z); o.s[3] = f2b(v.w);
  *(uint2*)(y + i) = o.u;
}

// ---------------- transpose f32 (RxC) -> bf16 (CxR) ----------------
__global__ void transpose_f32_bf16(const float* __restrict__ W, short* __restrict__ Wt,
                                   int R, int C) {
  __shared__ float tile[32][33];
  int c0 = blockIdx.x * 32, r0 = blockIdx.y * 32;
  int tx = threadIdx.x, ty = threadIdx.y;           // 32 x 8
  #pragma unroll
  for (int i = 0; i < 32; i += 8)
    tile[ty + i][tx] = W[(size_t)(r0 + ty + i) * C + c0 + tx];
  __syncthreads();
  #pragma unroll
  for (int i = 0; i < 32; i += 8)
    Wt[(size_t)(c0 + ty + i) * R + r0 + tx] = f2b(tile[tx][ty + i]);
}

// ---------------- 128x128 bf16 MFMA GEMM (proven m97 structure) ----------------
template<bool BIAS, bool OUTF32>
__global__ __launch_bounds__(256, 2) void gemm_bf16(
    const short* __restrict__ A, const short* __restrict__ Bt,
    const float* __restrict__ bias, short* __restrict__ outb,
    float* __restrict__ outf, int M, int N, int K)
{
  __shared__ short smA[128 * 64];
  __shared__ short smB[128 * 64];
  const int t = threadIdx.x;
  const int l = t & 63;
  const int w = t >> 6;
  const int wr = w >> 1, wc = w & 1;
  const int m0 = blockIdx.y * 128, n0 = blockIdx.x * 128;

  const f32x4 z = {0.f, 0.f, 0.f, 0.f};
  f32x4 acc[4][4];
  #pragma unroll
  for (int m = 0; m < 4; ++m)
    #pragma unroll
    for (int n = 0; n < 4; ++n) acc[m][n] = z;

  for (int k0 = 0; k0 < K; k0 += 64) {
    __syncthreads();
    #pragma unroll
    for (int i = 0; i < 4; ++i) {
      int c = t + i * 256;
      int row = c >> 3, slot = c & 7;
      int ss = slot ^ (row & 7);
      gll16(A  + (size_t)(m0 + row) * K + k0 + ss * 8,
            (char*)smA + (i * 256 + w * 64) * 16);
      gll16(Bt + (size_t)(n0 + row) * K + k0 + ss * 8,
            (char*)smB + (i * 256 + w * 64) * 16);
    }
    __syncthreads();
    #pragma unroll
    for (int kk = 0; kk < 2; ++kk) {
      bf16x8 a[4], b[4];
      #pragma unroll
      for (int m = 0; m < 4; ++m) {
        int row = wr * 64 + m * 16 + (l & 15);
        int off = (kk * 64 + ((l >> 4) << 4)) ^ ((row & 7) << 4);
        a[m] = *(const bf16x8*)((const char*)smA + row * 128 + off);
      }
      #pragma unroll
      for (int n = 0; n < 4; ++n) {
        int row = wc * 64 + n * 16 + (l & 15);
        int off = (kk * 64 + ((l >> 4) << 4)) ^ ((row & 7) << 4);
        b[n] = *(const bf16x8*)((const char*)smB + row * 128 + off);
      }
      #pragma unroll
      for (int m = 0; m < 4; ++m)
        #pragma unroll
        for (int n = 0; n < 4; ++n)
          acc[m][n] = __builtin_amdgcn_mfma_f32_16x16x32_bf16(a[m], b[n], acc[m][n], 0, 0, 0);
    }
  }

  #pragma unroll
  for (int m = 0; m < 4; ++m) {
    int row = m0 + wr * 64 + m * 16 + ((l >> 4) << 2);
    #pragma unroll
    for (int n = 0; n < 4; ++n) {
      int col = n0 + wc * 64 + n * 16 + (l & 15);
      float bv = BIAS ? bias[col] : 0.f;
      #pragma unroll
      for (int j = 0; j < 4; ++j) {
        float vv = acc[m][n][j] + bv;
        if (OUTF32) outf[(size_t)(row + j) * N + col] = vv;
        else        outb[(size_t)(row + j) * N + col] = f2b(vv);
      }
    }
  }
}

// ---------------- 256x256 8-phase counted-vmcnt bf16 GEMM (m201-style) ----------------
// 512 thr = 8 waves (2M x 4N), per-wave out 128x64. BK=64. LDS 128KiB = 2 tile-buffers,
// each {A 256x64 | B 256x64}, rows 128B, slot XOR (row&7) swizzle (conflict-free, proven).
// Per K-tile: 4 quadrant-phases; reads are one phase ahead (issued after the MFMA cluster);
// staging is one tile ahead in region order {A1@p0, B0@p1, B1@p2, A0@p3}; each region's last
// read drains (lgkmcnt(0)) a full barrier before its overwriting stage issues -> race-free.
// vmcnt(4) at p2 guarantees tile t+1 fully landed before its q0+B reads at p3. Never vmcnt(0).
__global__ __launch_bounds__(512, 2) void gemm256(
    const short* __restrict__ A, const short* __restrict__ Bt,
    float* __restrict__ outf, int M, int N, int K, int nbx)
{
  __shared__ char sm[131072];
  const int t = threadIdx.x, l = t & 63, w = t >> 6;
  const int lq = l & 15, hi = l >> 4;
  const int wm = w >> 2, wn = w & 3;
  const int nwg = (int)gridDim.x;
  const int oid = (int)blockIdx.x;
  const int swz = (oid & 7) * (nwg >> 3) + (oid >> 3);   // XCD swizzle (nwg % 8 == 0)
  const int by = swz / nbx, bx = swz - by * nbx;
  const int m0 = by * 256, n0 = bx * 256;
  const int nkt = K >> 6;

  auto stage = [&](int tt, int r) {     // region r: 0=B0 1=B1 2=A0 3=A1 of K-tile tt
    int kb = (tt < nkt ? tt : tt - nkt) << 6;
    const short* src = (r < 2) ? Bt + (size_t)(n0 + (r << 7)) * K + kb
                               : A  + (size_t)(m0 + ((r - 2) << 7)) * K + kb;
    char* dst = sm + ((tt & 1) << 16) + (r >= 2 ? 0 : 32768) + ((r & 1) << 14);
    #pragma unroll
    for (int i = 0; i < 2; ++i) {
      int c = (i << 9) + t;
      int row = c >> 3, ss = (c & 7) ^ (row & 7);
      gll16(src + (size_t)row * K + ss * 8, dst + ((i << 9) + (w << 6)) * 16);
    }
  };
  bf16x8 aC[2][2], bC[4][2];
  auto ldA = [&](int b, int q, bf16x8 (&out)[2][2]) {
    #pragma unroll
    for (int fr = 0; fr < 2; ++fr) {
      int ra = wm * 128 + q * 32 + fr * 16 + lq;
      #pragma unroll
      for (int kk = 0; kk < 2; ++kk)
        out[fr][kk] = *(const bf16x8*)(sm + (b << 16) + ra * 128 + (((kk << 2) + hi) ^ (ra & 7)) * 16);
    }
  };
  auto ldB = [&](int b, bf16x8 (&out)[4][2]) {
    #pragma unroll
    for (int fc = 0; fc < 4; ++fc) {
      int rb = wn * 64 + fc * 16 + lq;
      #pragma unroll
      for (int kk = 0; kk < 2; ++kk)
        out[fc][kk] = *(const bf16x8*)(sm + (b << 16) + 32768 + rb * 128 + (((kk << 2) + hi) ^ (rb & 7)) * 16);
    }
  };

  const f32x4 z = {0.f, 0.f, 0.f, 0.f};
  f32x4 acc[8][4];
  #pragma unroll
  for (int i = 0; i < 8; ++i)
    #pragma unroll
    for (int j = 0; j < 4; ++j) acc[i][j] = z;

  // prologue: tile0 all 4 halves + tile1 {B0,B1,A0}; 3 halves stay in flight
  stage(0, 0); stage(0, 1); stage(0, 2); stage(0, 3);
  stage(1, 0); stage(1, 1); stage(1, 2);
  asm volatile("s_waitcnt vmcnt(6)" ::: "memory");
  __builtin_amdgcn_s_barrier();
  ldB(0, bC); ldA(0, 0, aC);
  asm volatile("s_waitcnt lgkmcnt(0)" ::: "memory");

#define GPHASE(p, STG_T, STG_R)                                           \
  {                                                                       \
    stage((STG_T), (STG_R));                                              \
    __builtin_amdgcn_sched_barrier(0);                                    \
    __builtin_amdgcn_s_barrier();                                         \
    __builtin_amdgcn_s_setprio(1);                                        \
    _Pragma("unroll")                                                     \
    for (int kk = 0; kk < 2; ++kk)                                        \
      _Pragma("unroll")                                                   \
      for (int fr = 0; fr < 2; ++fr)                                      \
        _Pragma("unroll")                                                 \
        for (int fc = 0; fc < 4; ++fc)                                    \
          acc[(p) * 2 + fr][fc] = __builtin_amdgcn_mfma_f32_16x16x32_bf16(\
              aC[fr][kk], bC[fc][kk], acc[(p) * 2 + fr][fc], 0, 0, 0);    \
    __builtin_amdgcn_s_setprio(0);                                        \
    if ((p) < 3) ldA(bsel, (p) + 1, aC);                                  \
    else { ldA(bsel ^ 1, 0, aC); ldB(bsel ^ 1, bC); }                     \
    asm volatile("s_waitcnt lgkmcnt(0)" ::: "memory");                    \
    if ((p) == 2) asm volatile("s_waitcnt vmcnt(4)" ::: "memory");        \
    __builtin_amdgcn_s_barrier();                                         \
  }

  for (int tt = 0; tt < nkt; ++tt) {
    const int bsel = tt & 1;
    GPHASE(0, tt + 1, 3)
    GPHASE(1, tt + 2, 0)
    GPHASE(2, tt + 2, 1)
    GPHASE(3, tt + 2, 2)
  }
#undef GPHASE

  // epilogue: C rows m0 + wm*128 + q*32 + fr*16 + hi*4 + j, cols n0 + wn*64 + fc*16 + lq
  #pragma unroll
  for (int q = 0; q < 4; ++q)
    #pragma unroll
    for (int fr = 0; fr < 2; ++fr) {
      int gr0 = m0 + wm * 128 + q * 32 + fr * 16 + hi * 4;
      #pragma unroll
      for (int fc = 0; fc < 4; ++fc) {
        int col = n0 + wn * 64 + fc * 16 + lq;
        #pragma unroll
        for (int j = 0; j < 4; ++j)
          outf[(size_t)(gr0 + j) * N + col] = acc[q * 2 + fr][fc][j];
      }
    }
}

// ---------------- RoPE + split, vectorized (8 bf16/thread) ----------------
// q is pre-scaled by QSCALE (softmax runs in exp2 domain).
__global__ void rope_split(const short* __restrict__ mixed, const float* __restrict__ rope,
                           short* __restrict__ qo, short* __restrict__ ko, short* __restrict__ vo)
{
  const int CH = QKVN / 8;                 // 576 chunks per row
  int idx = blockIdx.x * blockDim.x + threadIdx.x;
  if (idx >= B_ * SQ * CH) return;
  int row = idx / CH;
  int cc = (idx - row * CH) * 8;
  int b = row >> 11, s = row & 2047;

  bf16x8 xv = *(const bf16x8*)(mixed + (size_t)row * QKVN + cc);
  float x[8];
  #pragma unroll
  for (int i = 0; i < 8; ++i) x[i] = b2f(xv[i]);

  int sect, hh, d = cc & 127;
  if (cc < 4096)      { sect = 0; hh = cc >> 7; }
  else if (cc < 4352) { sect = 1; hh = (cc - 4096) >> 7; }
  else                { sect = 2; hh = (cc - 4352) >> 7; }

  if (sect < 2 && d < 64) {                // rot_dim=64, interleaved pairs
    float4 ca = *(const float4*)(rope + s * 64 + d);
    float4 cb = *(const float4*)(rope + s * 64 + d + 4);
    float t0;
    t0 = x[0]*ca.x - x[1]*ca.y; x[1] = x[1]*ca.x + x[0]*ca.y; x[0] = t0;
    t0 = x[2]*ca.z - x[3]*ca.w; x[3] = x[3]*ca.z + x[2]*ca.w; x[2] = t0;
    t0 = x[4]*cb.x - x[5]*cb.y; x[5] = x[5]*cb.x + x[4]*cb.y; x[4] = t0;
    t0 = x[6]*cb.z - x[7]*cb.w; x[7] = x[7]*cb.z + x[6]*cb.w; x[6] = t0;
  }
  if (sect == 0) {
    #pragma unroll
    for (int i = 0; i < 8; ++i) x[i] *= QSCALE;
  }

  short* dst; size_t oidx;
  if (sect == 0)      { dst = qo; oidx = (((size_t)(b * NHEAD + hh) * SQ) + s) * HDIM + d; }
  else if (sect == 1) { dst = ko; oidx = (((size_t)(b * NGRP + hh) * SQ) + s) * HDIM + d; }
  else                { dst = vo; oidx = (((size_t)(b * NGRP + hh) * SQ) + s) * HDIM + d; }
  bf16x8 ov;
  #pragma unroll
  for (int i = 0; i < 8; ++i) ov[i] = f2b(x[i]);
  *(bf16x8*)(dst + oidx) = ov;
}

// ---------------- causal GQA flash attention ----------------
// grid (4, NH, B), 512 threads = 8 waves; block bx does super-tiles {bx, 7-bx} in two
// passes -> uniform 36 key-tiles/block. Swapped QK^T in-register softmax (exp2 domain),
// defer-max rescale, PV via 16x16x16 with in-lane P.
__global__ __launch_bounds__(512, 2) void attn_fwd(
    const short* __restrict__ q, const short* __restrict__ k,
    const short* __restrict__ v, short* __restrict__ ctx)
{
  __shared__ short smem[8192 + 9216];      // smK 64x128 (linear, swizzled), smV 128x72 (V^T)
  short* smK = smem;
  short* smV = smem + 8192;

  const int h = blockIdx.y, b = blockIdx.z;
  const int g = h >> 4;                    // GQA group
  const int t = threadIdx.x, l = t & 63, w = t >> 6;
  const int lq = l & 15, hi = l >> 4;

  const short* qbase = q + ((size_t)(b * NHEAD + h) * SQ) * HDIM;
  const short* kbase = k + ((size_t)(b * NGRP + g) * SQ) * HDIM;
  const short* vbase = v + ((size_t)(b * NGRP + g) * SQ) * HDIM;

  const f32x4 z = {0.f, 0.f, 0.f, 0.f};

  for (int pass = 0; pass < 2; ++pass) {
    const int s = pass ? (7 - (int)blockIdx.x) : (int)blockIdx.x;
    const int q0 = s * 256;
    const int qw = q0 + w * 32;
    const int nkt = 4 * s + 4;             // 64-key tiles for this pass

    bf16x8 qf[2][4];
    #pragma unroll
    for (int fq = 0; fq < 2; ++fq)
      #pragma unroll
      for (int kf = 0; kf < 4; ++kf)
        qf[fq][kf] = *(const bf16x8*)(qbase + (size_t)(qw + fq * 16 + lq) * HDIM + kf * 32 + hi * 8);

    f32x4 of[2][8];
    #pragma unroll
    for (int a = 0; a < 2; ++a)
      #pragma unroll
      for (int d = 0; d < 8; ++d) of[a][d] = z;
    float mrow[2] = {-1e30f, -1e30f};
    float lrow[2] = {0.f, 0.f};

    for (int kt = 0; kt < nkt; ++kt) {
      const int kb = kt * 64;
      __syncthreads();
      #pragma unroll
      for (int i = 0; i < 2; ++i) {
        int c = t + i * 512;
        int row = c >> 4, slot = c & 15;
        int ss = slot ^ (row & 7);
        gll16(kbase + (size_t)(kb + row) * HDIM + ss * 8,
              (char*)smK + (i * 512 + w * 64) * 16);
      }
      #pragma unroll
      for (int i = 0; i < 2; ++i) {
        int c = t + i * 512;
        int key = c & 63, d0 = (c >> 6) << 3;
        bf16x8 vv = *(const bf16x8*)(vbase + (size_t)(kb + key) * HDIM + d0);
        #pragma unroll
        for (int jj = 0; jj < 8; ++jj)
          smV[(d0 + jj) * 72 + key] = vv[jj];
      }
      __syncthreads();

      if (kb > qw + 31) continue;          // causal skip (barriers already done)

      f32x4 st[2][4];
      #pragma unroll
      for (int fq = 0; fq < 2; ++fq)
        #pragma unroll
        for (int fk = 0; fk < 4; ++fk) st[fq][fk] = z;
      #pragma unroll
      for (int kf = 0; kf < 4; ++kf) {
        bf16x8 kfr[4];
        #pragma unroll
        for (int fk = 0; fk < 4; ++fk) {
          int row = fk * 16 + lq;
          int slot = (kf * 4 + hi) ^ (row & 7);
          kfr[fk] = *(const bf16x8*)((const char*)smK + row * 256 + slot * 16);
        }
        #pragma unroll
        for (int fq = 0; fq < 2; ++fq)
          #pragma unroll
          for (int fk = 0; fk < 4; ++fk)
            st[fq][fk] = __builtin_amdgcn_mfma_f32_16x16x32_bf16(kfr[fk], qf[fq][kf], st[fq][fk], 0, 0, 0);
      }

      bf16x4 pa[2][4];
      #pragma unroll
      for (int fq = 0; fq < 2; ++fq) {
        float sv[16];
        #pragma unroll
        for (int fk = 0; fk < 4; ++fk)
          #pragma unroll
          for (int j = 0; j < 4; ++j) sv[fk * 4 + j] = st[fq][fk][j];
        if (kb + 63 > qw + fq * 16) {
          int qrow = qw + fq * 16 + lq;
          #pragma unroll
          for (int fk = 0; fk < 4; ++fk)
            #pragma unroll
            for (int j = 0; j < 4; ++j)
              if (kb + fk * 16 + hi * 4 + j > qrow) sv[fk * 4 + j] = -1e30f;
        }
        float mx = sv[0];
        #pragma unroll
        for (int i = 1; i < 16; ++i) mx = fmaxf(mx, sv[i]);
        mx = fmaxf(mx, __shfl_xor(mx, 16));
        mx = fmaxf(mx, __shfl_xor(mx, 32));
        if (__any(mx > mrow[fq] + 11.0f)) {
          float mn = fmaxf(mrow[fq], mx);
          float corr = exp2f(mrow[fq] - mn);
          mrow[fq] = mn;
          lrow[fq] *= corr;
          float cj[4];
          #pragma unroll
          for (int j = 0; j < 4; ++j) cj[j] = __shfl(corr, hi * 4 + j);
          #pragma unroll
          for (int df = 0; df < 8; ++df)
            #pragma unroll
            for (int j = 0; j < 4; ++j) of[fq][df][j] *= cj[j];
        }
        float rs = 0.f;
        #pragma unroll
        for (int i = 0; i < 16; ++i) { sv[i] = exp2f(sv[i] - mrow[fq]); rs += sv[i]; }
        rs += __shfl_xor(rs, 16);
        rs += __shfl_xor(rs, 32);
        lrow[fq] += rs;
        #pragma unroll
        for (int fk = 0; fk < 4; ++fk) {
          bf16x4 p;
          p[0] = f2b(sv[fk * 4 + 0]); p[1] = f2b(sv[fk * 4 + 1]);
          p[2] = f2b(sv[fk * 4 + 2]); p[3] = f2b(sv[fk * 4 + 3]);
          pa[fq][fk] = p;
        }
      }

      #pragma unroll
      for (int fk = 0; fk < 4; ++fk) {
        bf16x4 vb[8];
        #pragma unroll
        for (int df = 0; df < 8; ++df)
          vb[df] = *(const bf16x4*)(smV + (df * 16 + lq) * 72 + fk * 16 + hi * 4);
        #pragma unroll
        for (int df = 0; df < 8; ++df) {
          of[0][df] = __builtin_amdgcn_mfma_f32_16x16x16bf16_1k(pa[0][fk], vb[df], of[0][df], 0, 0, 0);
          of[1][df] = __builtin_amdgcn_mfma_f32_16x16x16bf16_1k(pa[1][fk], vb[df], of[1][df], 0, 0, 0);
        }
      }
    }

    #pragma unroll
    for (int fq = 0; fq < 2; ++fq) {
      float inv = 1.f / lrow[fq];
      float ij[4];
      #pragma unroll
      for (int j = 0; j < 4; ++j) ij[j] = __shfl(inv, hi * 4 + j);
      #pragma unroll
      for (int j = 0; j < 4; ++j) {
        int srow = qw + fq * 16 + hi * 4 + j;
        size_t rbase = ((size_t)(b * SQ + srow)) * (NHEAD * HDIM) + (size_t)h * HDIM;
        #pragma unroll
        for (int df = 0; df < 8; ++df)
          ctx[rbase + df * 16 + lq] = f2b(of[fq][df][j] * ij[j]);
      }
    }
    __syncthreads();   // protect LDS before next pass re-stages
  }
}

extern "C" void kernel_launch(void* const* d_in, const int* in_sizes, int n_in,
                              void* d_out, int out_size, void* d_ws, size_t ws_size,
                              hipStream_t stream)
{
  const float* hidden = (const float*)d_in[0];
  const float* rope   = (const float*)d_in[1];
  const float* Wqkv   = (const float*)d_in[2];
  const float* bqkv   = (const float*)d_in[3];
  const float* Wd     = (const float*)d_in[4];
  float* out = (float*)d_out;

  if (ws_size < 113246208ULL) return;
  char* ws = (char*)d_ws;
  short* hsb   = (short*)(ws);
  short* wT    = (short*)(ws + 33554432);
  short* mixed = (short*)(ws + 71303168);
  short* k_r   = (short*)(ws + 109051904);
  short* v_r   = (short*)(ws + 111149056);

  conv_f32_bf16<<<16384, 256, 0, stream>>>(hidden, hsb, B_ * SQ * H_);
  transpose_f32_bf16<<<dim3(QKVN / 32, H_ / 32), dim3(32, 8), 0, stream>>>(Wqkv, wT, H_, QKVN);
  gemm_bf16<true, false><<<dim3(QKVN / 128, (B_ * SQ) / 128), 256, 0, stream>>>(
      hsb, wT, bqkv, mixed, nullptr, B_ * SQ, QKVN, H_);
  rope_split<<<9216, 256, 0, stream>>>(mixed, rope, hsb, k_r, v_r);
  transpose_f32_bf16<<<dim3(H_ / 32, H_ / 32), dim3(32, 8), 0, stream>>>(Wd, wT, H_, H_);
  attn_fwd<<<dim3(4, NHEAD, B_), 512, 0, stream>>>(hsb, k_r, v_r, mixed);
  // dense: 256x256 8-phase counted-vmcnt GEMM; grid 16x16 = 256 blocks = 1/CU
  gemm256<<<256, 512, 0, stream>>>(mixed, wT, out, B_ * SQ, H_, H_, H_ / 256);
}

// Round 5
// 535.490 us; speedup vs baseline: 1.0260x; 1.0260x over previous
//
#include <hip/hip_runtime.h>
#include <hip/hip_bf16.h>
#include <stdint.h>

// Problem constants
#define B_    2
#define SQ    2048
#define H_    4096
#define NHEAD 32
#define HDIM  128
#define NGRP  2
#define QKVN  4608          // NH*HD + 2*NG*HD
#define SCALE 0.08838834764831845f   // 1/sqrt(128), coeff=1
#define QSCALE (0.08838834764831845f * 1.4426950408889634f)  // SCALE*log2(e), exp2 softmax

typedef __attribute__((ext_vector_type(8))) short bf16x8;
typedef __attribute__((ext_vector_type(4))) short bf16x4;
typedef __attribute__((ext_vector_type(4))) float f32x4;

__device__ __forceinline__ float b2f(short s) {
  union { float f; unsigned u; } x; x.u = ((unsigned)(unsigned short)s) << 16; return x.f;
}
__device__ __forceinline__ short f2b(float f) {
  union { float f; unsigned u; } x; x.f = f;
  unsigned r = x.u + 0x7fffu + ((x.u >> 16) & 1u);  // RNE
  return (short)(r >> 16);
}
__device__ __forceinline__ void gll16(const void* g, void* l) {
  __builtin_amdgcn_global_load_lds(
      (const __attribute__((address_space(1))) unsigned int*)g,
      (__attribute__((address_space(3))) unsigned int*)l, 16, 0, 0);
}

// ---------------- f32 -> bf16 convert (vectorized) ----------------
__global__ void conv_f32_bf16(const float* __restrict__ x, short* __restrict__ y, int n) {
  int i = (blockIdx.x * blockDim.x + threadIdx.x) * 4;
  if (i >= n) return;
  float4 v = *(const float4*)(x + i);
  union { short s[4]; uint2 u; } o;
  o.s[0] = f2b(v.x); o.s[1] = f2b(v.y); o.s[2] = f2b(v.z); o.s[3] = f2b(v.w);
  *(uint2*)(y + i) = o.u;
}

// ---------------- transpose f32 (RxC) -> bf16 (CxR) ----------------
__global__ void transpose_f32_bf16(const float* __restrict__ W, short* __restrict__ Wt,
                                   int R, int C) {
  __shared__ float tile[32][33];
  int c0 = blockIdx.x * 32, r0 = blockIdx.y * 32;
  int tx = threadIdx.x, ty = threadIdx.y;           // 32 x 8
  #pragma unroll
  for (int i = 0; i < 32; i += 8)
    tile[ty + i][tx] = W[(size_t)(r0 + ty + i) * C + c0 + tx];
  __syncthreads();
  #pragma unroll
  for (int i = 0; i < 32; i += 8)
    Wt[(size_t)(c0 + ty + i) * R + r0 + tx] = f2b(tile[tx][ty + i]);
}

// ---------------- 128x128 bf16 MFMA GEMM (proven m97 structure) ----------------
template<bool BIAS, bool OUTF32>
__global__ __launch_bounds__(256, 2) void gemm_bf16(
    const short* __restrict__ A, const short* __restrict__ Bt,
    const float* __restrict__ bias, short* __restrict__ outb,
    float* __restrict__ outf, int M, int N, int K)
{
  __shared__ short smA[128 * 64];
  __shared__ short smB[128 * 64];
  const int t = threadIdx.x;
  const int l = t & 63;
  const int w = t >> 6;
  const int wr = w >> 1, wc = w & 1;
  const int m0 = blockIdx.y * 128, n0 = blockIdx.x * 128;

  const f32x4 z = {0.f, 0.f, 0.f, 0.f};
  f32x4 acc[4][4];
  #pragma unroll
  for (int m = 0; m < 4; ++m)
    #pragma unroll
    for (int n = 0; n < 4; ++n) acc[m][n] = z;

  for (int k0 = 0; k0 < K; k0 += 64) {
    __syncthreads();
    #pragma unroll
    for (int i = 0; i < 4; ++i) {
      int c = t + i * 256;
      int row = c >> 3, slot = c & 7;
      int ss = slot ^ (row & 7);
      gll16(A  + (size_t)(m0 + row) * K + k0 + ss * 8,
            (char*)smA + (i * 256 + w * 64) * 16);
      gll16(Bt + (size_t)(n0 + row) * K + k0 + ss * 8,
            (char*)smB + (i * 256 + w * 64) * 16);
    }
    __syncthreads();
    #pragma unroll
    for (int kk = 0; kk < 2; ++kk) {
      bf16x8 a[4], b[4];
      #pragma unroll
      for (int m = 0; m < 4; ++m) {
        int row = wr * 64 + m * 16 + (l & 15);
        int off = (kk * 64 + ((l >> 4) << 4)) ^ ((row & 7) << 4);
        a[m] = *(const bf16x8*)((const char*)smA + row * 128 + off);
      }
      #pragma unroll
      for (int n = 0; n < 4; ++n) {
        int row = wc * 64 + n * 16 + (l & 15);
        int off = (kk * 64 + ((l >> 4) << 4)) ^ ((row & 7) << 4);
        b[n] = *(const bf16x8*)((const char*)smB + row * 128 + off);
      }
      #pragma unroll
      for (int m = 0; m < 4; ++m)
        #pragma unroll
        for (int n = 0; n < 4; ++n)
          acc[m][n] = __builtin_amdgcn_mfma_f32_16x16x32_bf16(a[m], b[n], acc[m][n], 0, 0, 0);
    }
  }

  #pragma unroll
  for (int m = 0; m < 4; ++m) {
    int row = m0 + wr * 64 + m * 16 + ((l >> 4) << 2);
    #pragma unroll
    for (int n = 0; n < 4; ++n) {
      int col = n0 + wc * 64 + n * 16 + (l & 15);
      float bv = BIAS ? bias[col] : 0.f;
      #pragma unroll
      for (int j = 0; j < 4; ++j) {
        float vv = acc[m][n][j] + bv;
        if (OUTF32) outf[(size_t)(row + j) * N + col] = vv;
        else        outb[(size_t)(row + j) * N + col] = f2b(vv);
      }
    }
  }
}

// ---------------- 256x256 4-phase counted-vmcnt bf16 GEMM ----------------
// 512 thr = 8 waves (2M x 4N), per-wave out 128x64, BK=64. LDS 128KiB = 2 tile-bufs
// {A 256x64 | B 256x64}, 128B rows, slot XOR (row&7) (conflict-free, counter-proven).
// Phase p of tile T: { ds-read quadrant-p operands (+B at p0) from buf T&1;
//   stage unit p of tile T+1 into buf (T+1)&1; s_barrier; [compiler lgkmcnt]
//   setprio(1); 16 MFMA; setprio(0); [vmcnt] ; s_barrier }.
// Stage units: {0=B rows0-127, 1=B rows128-255, 2=A rows{0-63,128-191} (quadrants 0,1),
// 3=A rows{64-127,192-255} (quadrants 2,3)} -- chosen so every region a phase reads was
// staged >=2 phases earlier. Per-wave vmcnt ledger (2 loads/unit): steady-state
// outstanding at p1-end = {unit3(T), unit0(T+1), unit1(T+1)} = 6 -> vmcnt(4) drains
// unit3(T) before its first read at p2; at p3-end = {units0..3(T+1)} = 8 -> vmcnt(2)
// drains B0,B1,Aq01(T+1) before tile T+1's p0/p1 reads. Never vmcnt(0) in-loop.
__global__ __launch_bounds__(512, 2) void gemm256(
    const short* __restrict__ A, const short* __restrict__ Bt,
    float* __restrict__ outf, int M, int N, int K, int nbx)
{
  __shared__ char sm[131072];
  const int t = threadIdx.x, l = t & 63, w = t >> 6;
  const int lq = l & 15, hi = l >> 4;
  const int wm = w >> 2, wn = w & 3;
  const int nwg = (int)gridDim.x;
  const int oid = (int)blockIdx.x;
  const int swz = (oid & 7) * (nwg >> 3) + (oid >> 3);   // XCD swizzle (nwg % 8 == 0)
  const int by = swz / nbx, bx = swz - by * nbx;
  const int m0 = by * 256, n0 = bx * 256;
  const int nkt = K >> 6;

  auto stage = [&](int tt, int u) {        // stage unit u of K-tile tt into buf tt&1
    int kb = (tt < nkt ? tt : tt - nkt) << 6;
    char* buf = sm + ((tt & 1) << 16);
    #pragma unroll
    for (int i = 0; i < 2; ++i) {
      int c = (i << 9) + t;
      int grow = (u < 2) ? (c >> 3) + ((u & 1) << 7)
                         : (c >> 3) + (i << 6) + ((u & 1) << 6);
      int ss = (c & 7) ^ (grow & 7);
      const short* src = (u < 2) ? Bt + (size_t)(n0 + grow) * K + kb + ss * 8
                                 : A  + (size_t)(m0 + grow) * K + kb + ss * 8;
      gll16(src, buf + (u < 2 ? 32768 : 0) + grow * 128 + (c & 7) * 16);
    }
  };

  bf16x8 aC[2][2], bC[4][2];
  auto ldA = [&](int b, int q) {
    #pragma unroll
    for (int fr = 0; fr < 2; ++fr) {
      int ra = wm * 128 + q * 32 + fr * 16 + lq;
      #pragma unroll
      for (int kk = 0; kk < 2; ++kk)
        aC[fr][kk] = *(const bf16x8*)(sm + (b << 16) + ra * 128 + (((kk << 2) + hi) ^ (ra & 7)) * 16);
    }
  };
  auto ldB = [&](int b) {
    #pragma unroll
    for (int fc = 0; fc < 4; ++fc) {
      int rb = wn * 64 + fc * 16 + lq;
      #pragma unroll
      for (int kk = 0; kk < 2; ++kk)
        bC[fc][kk] = *(const bf16x8*)(sm + (b << 16) + 32768 + rb * 128 + (((kk << 2) + hi) ^ (rb & 7)) * 16);
    }
  };

  const f32x4 z = {0.f, 0.f, 0.f, 0.f};
  f32x4 acc[8][4];
  #pragma unroll
  for (int i = 0; i < 8; ++i)
    #pragma unroll
    for (int j = 0; j < 4; ++j) acc[i][j] = z;

  // prologue: tile0 fully staged (one-time full drain; in-loop waits are counted)
  stage(0, 0); stage(0, 1); stage(0, 2); stage(0, 3);
  asm volatile("s_waitcnt vmcnt(0)" ::: "memory");
  __builtin_amdgcn_s_barrier();

#define GPHASE(Q, VM)                                                     \
  {                                                                       \
    if ((Q) == 0) ldB(bsel);                                              \
    ldA(bsel, (Q));                                                       \
    stage(T + 1, (Q));                                                    \
    __builtin_amdgcn_s_barrier();                                         \
    __builtin_amdgcn_s_setprio(1);                                        \
    _Pragma("unroll")                                                     \
    for (int kk = 0; kk < 2; ++kk)                                        \
      _Pragma("unroll")                                                   \
      for (int fr = 0; fr < 2; ++fr)                                      \
        _Pragma("unroll")                                                 \
        for (int fc = 0; fc < 4; ++fc)                                    \
          acc[(Q) * 2 + fr][fc] = __builtin_amdgcn_mfma_f32_16x16x32_bf16(\
              aC[fr][kk], bC[fc][kk], acc[(Q) * 2 + fr][fc], 0, 0, 0);    \
    __builtin_amdgcn_s_setprio(0);                                        \
    if ((VM) == 4) asm volatile("s_waitcnt vmcnt(4)" ::: "memory");       \
    if ((VM) == 2) asm volatile("s_waitcnt vmcnt(2)" ::: "memory");       \
    __builtin_amdgcn_s_barrier();                                         \
  }

  for (int T = 0; T < nkt; ++T) {
    const int bsel = T & 1;
    GPHASE(0, -1)
    GPHASE(1, 4)
    GPHASE(2, -1)
    GPHASE(3, 2)
  }
#undef GPHASE

  // epilogue: C rows m0 + wm*128 + q*32 + fr*16 + hi*4 + j, cols n0 + wn*64 + fc*16 + lq
  #pragma unroll
  for (int q = 0; q < 4; ++q)
    #pragma unroll
    for (int fr = 0; fr < 2; ++fr) {
      int gr0 = m0 + wm * 128 + q * 32 + fr * 16 + hi * 4;
      #pragma unroll
      for (int fc = 0; fc < 4; ++fc) {
        int col = n0 + wn * 64 + fc * 16 + lq;
        #pragma unroll
        for (int j = 0; j < 4; ++j)
          outf[(size_t)(gr0 + j) * N + col] = acc[q * 2 + fr][fc][j];
      }
    }
}

// ---------------- RoPE + split, vectorized (8 bf16/thread) ----------------
// q is pre-scaled by QSCALE (softmax runs in exp2 domain).
__global__ void rope_split(const short* __restrict__ mixed, const float* __restrict__ rope,
                           short* __restrict__ qo, short* __restrict__ ko, short* __restrict__ vo)
{
  const int CH = QKVN / 8;                 // 576 chunks per row
  int idx = blockIdx.x * blockDim.x + threadIdx.x;
  if (idx >= B_ * SQ * CH) return;
  int row = idx / CH;
  int cc = (idx - row * CH) * 8;
  int b = row >> 11, s = row & 2047;

  bf16x8 xv = *(const bf16x8*)(mixed + (size_t)row * QKVN + cc);
  float x[8];
  #pragma unroll
  for (int i = 0; i < 8; ++i) x[i] = b2f(xv[i]);

  int sect, hh, d = cc & 127;
  if (cc < 4096)      { sect = 0; hh = cc >> 7; }
  else if (cc < 4352) { sect = 1; hh = (cc - 4096) >> 7; }
  else                { sect = 2; hh = (cc - 4352) >> 7; }

  if (sect < 2 && d < 64) {                // rot_dim=64, interleaved pairs
    float4 ca = *(const float4*)(rope + s * 64 + d);
    float4 cb = *(const float4*)(rope + s * 64 + d + 4);
    float t0;
    t0 = x[0]*ca.x - x[1]*ca.y; x[1] = x[1]*ca.x + x[0]*ca.y; x[0] = t0;
    t0 = x[2]*ca.z - x[3]*ca.w; x[3] = x[3]*ca.z + x[2]*ca.w; x[2] = t0;
    t0 = x[4]*cb.x - x[5]*cb.y; x[5] = x[5]*cb.x + x[4]*cb.y; x[4] = t0;
    t0 = x[6]*cb.z - x[7]*cb.w; x[7] = x[7]*cb.z + x[6]*cb.w; x[6] = t0;
  }
  if (sect == 0) {
    #pragma unroll
    for (int i = 0; i < 8; ++i) x[i] *= QSCALE;
  }

  short* dst; size_t oidx;
  if (sect == 0)      { dst = qo; oidx = (((size_t)(b * NHEAD + hh) * SQ) + s) * HDIM + d; }
  else if (sect == 1) { dst = ko; oidx = (((size_t)(b * NGRP + hh) * SQ) + s) * HDIM + d; }
  else                { dst = vo; oidx = (((size_t)(b * NGRP + hh) * SQ) + s) * HDIM + d; }
  bf16x8 ov;
  #pragma unroll
  for (int i = 0; i < 8; ++i) ov[i] = f2b(x[i]);
  *(bf16x8*)(dst + oidx) = ov;
}

// ---------------- causal GQA flash attention ----------------
// grid (4, NH, B), 512 threads = 8 waves; block bx does super-tiles {bx, 7-bx} in two
// passes -> uniform 36 key-tiles/block. Swapped QK^T in-register softmax (exp2 domain),
// defer-max rescale, PV via 16x16x16 with in-lane P.
__global__ __launch_bounds__(512, 2) void attn_fwd(
    const short* __restrict__ q, const short* __restrict__ k,
    const short* __restrict__ v, short* __restrict__ ctx)
{
  __shared__ short smem[8192 + 9216];      // smK 64x128 (linear, swizzled), smV 128x72 (V^T)
  short* smK = smem;
  short* smV = smem + 8192;

  const int h = blockIdx.y, b = blockIdx.z;
  const int g = h >> 4;                    // GQA group
  const int t = threadIdx.x, l = t & 63, w = t >> 6;
  const int lq = l & 15, hi = l >> 4;

  const short* qbase = q + ((size_t)(b * NHEAD + h) * SQ) * HDIM;
  const short* kbase = k + ((size_t)(b * NGRP + g) * SQ) * HDIM;
  const short* vbase = v + ((size_t)(b * NGRP + g) * SQ) * HDIM;

  const f32x4 z = {0.f, 0.f, 0.f, 0.f};

  for (int pass = 0; pass < 2; ++pass) {
    const int s = pass ? (7 - (int)blockIdx.x) : (int)blockIdx.x;
    const int q0 = s * 256;
    const int qw = q0 + w * 32;
    const int nkt = 4 * s + 4;             // 64-key tiles for this pass

    bf16x8 qf[2][4];
    #pragma unroll
    for (int fq = 0; fq < 2; ++fq)
      #pragma unroll
      for (int kf = 0; kf < 4; ++kf)
        qf[fq][kf] = *(const bf16x8*)(qbase + (size_t)(qw + fq * 16 + lq) * HDIM + kf * 32 + hi * 8);

    f32x4 of[2][8];
    #pragma unroll
    for (int a = 0; a < 2; ++a)
      #pragma unroll
      for (int d = 0; d < 8; ++d) of[a][d] = z;
    float mrow[2] = {-1e30f, -1e30f};
    float lrow[2] = {0.f, 0.f};

    for (int kt = 0; kt < nkt; ++kt) {
      const int kb = kt * 64;
      __syncthreads();
      #pragma unroll
      for (int i = 0; i < 2; ++i) {
        int c = t + i * 512;
        int row = c >> 4, slot = c & 15;
        int ss = slot ^ (row & 7);
        gll16(kbase + (size_t)(kb + row) * HDIM + ss * 8,
              (char*)smK + (i * 512 + w * 64) * 16);
      }
      #pragma unroll
      for (int i = 0; i < 2; ++i) {
        int c = t + i * 512;
        int key = c & 63, d0 = (c >> 6) << 3;
        bf16x8 vv = *(const bf16x8*)(vbase + (size_t)(kb + key) * HDIM + d0);
        #pragma unroll
        for (int jj = 0; jj < 8; ++jj)
          smV[(d0 + jj) * 72 + key] = vv[jj];
      }
      __syncthreads();

      if (kb > qw + 31) continue;          // causal skip (barriers already done)

      f32x4 st[2][4];
      #pragma unroll
      for (int fq = 0; fq < 2; ++fq)
        #pragma unroll
        for (int fk = 0; fk < 4; ++fk) st[fq][fk] = z;
      #pragma unroll
      for (int kf = 0; kf < 4; ++kf) {
        bf16x8 kfr[4];
        #pragma unroll
        for (int fk = 0; fk < 4; ++fk) {
          int row = fk * 16 + lq;
          int slot = (kf * 4 + hi) ^ (row & 7);
          kfr[fk] = *(const bf16x8*)((const char*)smK + row * 256 + slot * 16);
        }
        #pragma unroll
        for (int fq = 0; fq < 2; ++fq)
          #pragma unroll
          for (int fk = 0; fk < 4; ++fk)
            st[fq][fk] = __builtin_amdgcn_mfma_f32_16x16x32_bf16(kfr[fk], qf[fq][kf], st[fq][fk], 0, 0, 0);
      }

      bf16x4 pa[2][4];
      #pragma unroll
      for (int fq = 0; fq < 2; ++fq) {
        float sv[16];
        #pragma unroll
        for (int fk = 0; fk < 4; ++fk)
          #pragma unroll
          for (int j = 0; j < 4; ++j) sv[fk * 4 + j] = st[fq][fk][j];
        if (kb + 63 > qw + fq * 16) {
          int qrow = qw + fq * 16 + lq;
          #pragma unroll
          for (int fk = 0; fk < 4; ++fk)
            #pragma unroll
            for (int j = 0; j < 4; ++j)
              if (kb + fk * 16 + hi * 4 + j > qrow) sv[fk * 4 + j] = -1e30f;
        }
        float mx = sv[0];
        #pragma unroll
        for (int i = 1; i < 16; ++i) mx = fmaxf(mx, sv[i]);
        mx = fmaxf(mx, __shfl_xor(mx, 16));
        mx = fmaxf(mx, __shfl_xor(mx, 32));
        if (__any(mx > mrow[fq] + 11.0f)) {
          float mn = fmaxf(mrow[fq], mx);
          float corr = exp2f(mrow[fq] - mn);
          mrow[fq] = mn;
          lrow[fq] *= corr;
          float cj[4];
          #pragma unroll
          for (int j = 0; j < 4; ++j) cj[j] = __shfl(corr, hi * 4 + j);
          #pragma unroll
          for (int df = 0; df < 8; ++df)
            #pragma unroll
            for (int j = 0; j < 4; ++j) of[fq][df][j] *= cj[j];
        }
        float rs = 0.f;
        #pragma unroll
        for (int i = 0; i < 16; ++i) { sv[i] = exp2f(sv[i] - mrow[fq]); rs += sv[i]; }
        rs += __shfl_xor(rs, 16);
        rs += __shfl_xor(rs, 32);
        lrow[fq] += rs;
        #pragma unroll
        for (int fk = 0; fk < 4; ++fk) {
          bf16x4 p;
          p[0] = f2b(sv[fk * 4 + 0]); p[1] = f2b(sv[fk * 4 + 1]);
          p[2] = f2b(sv[fk * 4 + 2]); p[3] = f2b(sv[fk * 4 + 3]);
          pa[fq][fk] = p;
        }
      }

      #pragma unroll
      for (int fk = 0; fk < 4; ++fk) {
        bf16x4 vb[8];
        #pragma unroll
        for (int df = 0; df < 8; ++df)
          vb[df] = *(const bf16x4*)(smV + (df * 16 + lq) * 72 + fk * 16 + hi * 4);
        #pragma unroll
        for (int df = 0; df < 8; ++df) {
          of[0][df] = __builtin_amdgcn_mfma_f32_16x16x16bf16_1k(pa[0][fk], vb[df], of[0][df], 0, 0, 0);
          of[1][df] = __builtin_amdgcn_mfma_f32_16x16x16bf16_1k(pa[1][fk], vb[df], of[1][df], 0, 0, 0);
        }
      }
    }

    #pragma unroll
    for (int fq = 0; fq < 2; ++fq) {
      float inv = 1.f / lrow[fq];
      float ij[4];
      #pragma unroll
      for (int j = 0; j < 4; ++j) ij[j] = __shfl(inv, hi * 4 + j);
      #pragma unroll
      for (int j = 0; j < 4; ++j) {
        int srow = qw + fq * 16 + hi * 4 + j;
        size_t rbase = ((size_t)(b * SQ + srow)) * (NHEAD * HDIM) + (size_t)h * HDIM;
        #pragma unroll
        for (int df = 0; df < 8; ++df)
          ctx[rbase + df * 16 + lq] = f2b(of[fq][df][j] * ij[j]);
      }
    }
    __syncthreads();   // protect LDS before next pass re-stages
  }
}

extern "C" void kernel_launch(void* const* d_in, const int* in_sizes, int n_in,
                              void* d_out, int out_size, void* d_ws, size_t ws_size,
                              hipStream_t stream)
{
  const float* hidden = (const float*)d_in[0];
  const float* rope   = (const float*)d_in[1];
  const float* Wqkv   = (const float*)d_in[2];
  const float* bqkv   = (const float*)d_in[3];
  const float* Wd     = (const float*)d_in[4];
  float* out = (float*)d_out;

  if (ws_size < 113246208ULL) return;
  char* ws = (char*)d_ws;
  short* hsb   = (short*)(ws);
  short* wT    = (short*)(ws + 33554432);
  short* mixed = (short*)(ws + 71303168);
  short* k_r   = (short*)(ws + 109051904);
  short* v_r   = (short*)(ws + 111149056);

  conv_f32_bf16<<<16384, 256, 0, stream>>>(hidden, hsb, B_ * SQ * H_);
  transpose_f32_bf16<<<dim3(QKVN / 32, H_ / 32), dim3(32, 8), 0, stream>>>(Wqkv, wT, H_, QKVN);
  gemm_bf16<true, false><<<dim3(QKVN / 128, (B_ * SQ) / 128), 256, 0, stream>>>(
      hsb, wT, bqkv, mixed, nullptr, B_ * SQ, QKVN, H_);
  rope_split<<<9216, 256, 0, stream>>>(mixed, rope, hsb, k_r, v_r);
  transpose_f32_bf16<<<dim3(H_ / 32, H_ / 32), dim3(32, 8), 0, stream>>>(Wd, wT, H_, H_);
  attn_fwd<<<dim3(4, NHEAD, B_), 512, 0, stream>>>(hsb, k_r, v_r, mixed);
  // dense: 256x256 4-phase counted-vmcnt GEMM; grid 16x16 = 256 blocks = 1/CU
  gemm256<<<256, 512, 0, stream>>>(mixed, wT, out, B_ * SQ, H_, H_, H_ / 256);
}